// Round 1
// baseline (11648.341 us; speedup 1.0000x reference)
//
#include <hip/hip_runtime.h>
#include <hip/hip_bf16.h>

// LMU cell, MI355X. Phases:
//  K0: convert Wh -> Wh2T (bf16, [512 n][4096 k], Wh stacked twice for hi/lo m split),
//      Uh -> bf16.
//  K1: u[bm][t] = x@kernel  (f32)
//  K2: sequential m-scan over t (f32 state in LDS, A columns in VGPRs),
//      writes m as bf16 hi/lo into chunk buffer [128*64 rows][4096]
//  K3: pre = m@Wh + bh as bf16 MFMA GEMM (K=4096), writes pre INTO d_out[b][t][h]
//  K4: h_t = tanh(pre_t + h_{t-1}@Uh): 32 blocks = 4 batch-groups x 8 hidden-slices,
//      Uh^T slice in LDS, per-step 8-block spin barrier, in-place on d_out,
//      h-exchange read from d_out[t-1].

#define T_SEQ 1024
#define BATCHN 64
#define MEMD 32
#define ORD 64
#define HID 512
#define DIN 128
#define NROWS 2048            // BATCHN*MEMD
#define KDIM 4096             // 2*MEMD*ORD (hi | lo)
#define TCH 128
#define NCHUNK 8

typedef __attribute__((ext_vector_type(4))) float f32x4;
typedef __attribute__((ext_vector_type(8))) __bf16 bf16x8;

static __device__ __forceinline__ unsigned short f2bf(float f) {
    __hip_bfloat16 h = __float2bfloat16(f);
    return *reinterpret_cast<unsigned short*>(&h);
}
static __device__ __forceinline__ float bf2f(unsigned short s) {
    __hip_bfloat16 h = *reinterpret_cast<__hip_bfloat16*>(&s);
    return __bfloat162float(h);
}

// ---------------- K0: weight conversion ----------------
__global__ __launch_bounds__(256) void k0_convert(
        const float* __restrict__ Wh, const float* __restrict__ Uh,
        unsigned short* __restrict__ Wh2T, unsigned short* __restrict__ Uhb) {
    const int total = HID * KDIM + HID * HID;
    for (int idx = blockIdx.x * 256 + threadIdx.x; idx < total; idx += gridDim.x * 256) {
        if (idx < HID * KDIM) {
            int n = idx >> 12;          // /4096
            int k = idx & 4095;
            int ks = (k >= 2048) ? (k - 2048) : k;   // Wh stacked twice
            Wh2T[idx] = f2bf(Wh[(size_t)ks * HID + n]);
        } else {
            int j = idx - HID * KDIM;
            Uhb[j] = f2bf(Uh[j]);
        }
    }
}

// ---------------- K1: u = x @ kernel -> u[bm][t] ----------------
__global__ __launch_bounds__(256) void k1_ugemm(
        const float* __restrict__ x, const float* __restrict__ kern,
        float* __restrict__ u) {
    __shared__ float xs[64 * 128];
    __shared__ float kT[32 * 129];
    const int b = blockIdx.x >> 4;
    const int tt = blockIdx.x & 15;
    const int t0 = tt * 64;
    const int tid = threadIdx.x;

    const float4* xg = reinterpret_cast<const float4*>(x + ((size_t)b * T_SEQ + t0) * DIN);
    float4* xs4 = reinterpret_cast<float4*>(xs);
    #pragma unroll
    for (int r = 0; r < 8; ++r) xs4[r * 256 + tid] = xg[r * 256 + tid];
    #pragma unroll
    for (int r = 0; r < 16; ++r) {
        int idx = r * 256 + tid;        // 4096 = 128 d * 32 m
        int d = idx >> 5, m = idx & 31;
        kT[m * 129 + d] = kern[idx];
    }
    __syncthreads();

    const int m = tid & 31, tq = tid >> 5;
    float acc[8];
    #pragma unroll
    for (int i = 0; i < 8; ++i) acc[i] = 0.f;
    #pragma unroll
    for (int d4 = 0; d4 < 32; ++d4) {
        float k0 = kT[m * 129 + d4 * 4 + 0];
        float k1 = kT[m * 129 + d4 * 4 + 1];
        float k2 = kT[m * 129 + d4 * 4 + 2];
        float k3 = kT[m * 129 + d4 * 4 + 3];
        #pragma unroll
        for (int i = 0; i < 8; ++i) {
            float4 xv = xs4[(tq * 8 + i) * 32 + d4];
            acc[i] += xv.x * k0 + xv.y * k1 + xv.z * k2 + xv.w * k3;
        }
    }
    #pragma unroll
    for (int i = 0; i < 8; ++i)
        u[((size_t)(b * MEMD + m)) * T_SEQ + t0 + tq * 8 + i] = acc[i];
}

// ---------------- K2: m-scan (f32), writes bf16 hi/lo ----------------
// 256 blocks x 256 thr. Block owns 8 rows (bm). Wave = 2 rows x 32 p-lanes,
// each lane handles p0=2*pl, p0+1. A columns cached in VGPRs.
__global__ __launch_bounds__(256, 1) void k2_mscan(
        const float* __restrict__ u, const float* __restrict__ A,
        const float* __restrict__ Bv, float* __restrict__ m_state,
        unsigned short* __restrict__ m_buf, int t0) {
    __shared__ float mbuf[2][8][64];
    __shared__ float ul[8][128];
    const int tid = threadIdx.x;
    const int wv = tid >> 6, half = (tid >> 5) & 1, pl = tid & 31;
    const int rl = wv * 2 + half;           // local row 0..7
    const int r = blockIdx.x * 8 + rl;      // global row (b*32+mem)
    const int p0 = pl * 2;

    float A0[64], A1[64];
    #pragma unroll
    for (int o = 0; o < 64; ++o) {
        A0[o] = A[o * 64 + p0];
        A1[o] = A[o * 64 + p0 + 1];
    }
    const float B0 = Bv[p0], B1 = Bv[p0 + 1];

    {   // stage u chunk: [8 rows][128 t]
        int row = tid >> 5, c4 = (tid & 31) * 4;
        *(float4*)&ul[row][c4] =
            *(const float4*)&u[(size_t)(blockIdx.x * 8 + row) * T_SEQ + t0 + c4];
    }
    float mc0, mc1;
    if (t0 == 0) { mc0 = 0.f; mc1 = 0.f; }
    else { mc0 = m_state[r * 64 + p0]; mc1 = m_state[r * 64 + p0 + 1]; }
    mbuf[0][rl][p0] = mc0;
    mbuf[0][rl][p0 + 1] = mc1;
    __syncthreads();

    const int b = r >> 5, mem = r & 31;
    int cur = 0;
    for (int tl = 0; tl < TCH; ++tl) {
        const float ut = ul[rl][tl];
        float a0 = ut * B0, a1 = ut * B1;
        const float4* mrow = (const float4*)&mbuf[cur][rl][0];
        #pragma unroll
        for (int o4 = 0; o4 < 16; ++o4) {
            float4 mv = mrow[o4];
            a0 += mv.x * A0[o4 * 4] + mv.y * A0[o4 * 4 + 1] + mv.z * A0[o4 * 4 + 2] + mv.w * A0[o4 * 4 + 3];
            a1 += mv.x * A1[o4 * 4] + mv.y * A1[o4 * 4 + 1] + mv.z * A1[o4 * 4 + 2] + mv.w * A1[o4 * 4 + 3];
        }
        // split store: hi + lo (residual) bf16
        size_t rowg = (size_t)(tl * 64 + b) * KDIM + mem * 64 + p0;
        unsigned short h0 = f2bf(a0), h1 = f2bf(a1);
        float f0 = a0 - bf2f(h0);
        float f1 = a1 - bf2f(h1);
        ushort2 hv; hv.x = h0; hv.y = h1;
        ushort2 lv; lv.x = f2bf(f0); lv.y = f2bf(f1);
        *(ushort2*)&m_buf[rowg] = hv;
        *(ushort2*)&m_buf[rowg + 2048] = lv;
        mbuf[cur ^ 1][rl][p0] = a0;
        mbuf[cur ^ 1][rl][p0 + 1] = a1;
        mc0 = a0; mc1 = a1;
        cur ^= 1;
        __syncthreads();
    }
    m_state[r * 64 + p0] = mc0;
    m_state[r * 64 + p0 + 1] = mc1;
}

// ---------------- K3: pre = m @ Wh + bh  (bf16 MFMA, K=4096) ----------------
// BM=128 BN=128 BK=64, 256 thr (4 waves, each 64x64). Writes pre into d_out[b][t][h].
__global__ __launch_bounds__(256, 1) void k3_gemm(
        const unsigned short* __restrict__ m_chunk,
        const unsigned short* __restrict__ Wh2T,
        const float* __restrict__ bh,
        float* __restrict__ out, int t0) {
    __shared__ short As[128 * 72];
    __shared__ short Bs[128 * 72];
    const int tid = threadIdx.x;
    const int l = tid & 63, wv = tid >> 6;
    const int wr = wv >> 1, wc = wv & 1;
    const int row0 = blockIdx.x * 128, n0 = blockIdx.y * 128;

    f32x4 acc[4][4];
    #pragma unroll
    for (int i = 0; i < 4; ++i)
        #pragma unroll
        for (int j = 0; j < 4; ++j)
            acc[i][j] = (f32x4){0.f, 0.f, 0.f, 0.f};

    for (int k0 = 0; k0 < KDIM; k0 += 64) {
        int4 av[4], bv[4];
        #pragma unroll
        for (int rI = 0; rI < 4; ++rI) {
            int idx = rI * 256 + tid;
            int rr = idx >> 3, l8 = idx & 7;
            av[rI] = *(const int4*)(m_chunk + (size_t)(row0 + rr) * KDIM + k0 + l8 * 8);
            bv[rI] = *(const int4*)(Wh2T + (size_t)(n0 + rr) * KDIM + k0 + l8 * 8);
        }
        __syncthreads();   // prior MFMA frag reads done
        #pragma unroll
        for (int rI = 0; rI < 4; ++rI) {
            int idx = rI * 256 + tid;
            int rr = idx >> 3, l8 = idx & 7;
            *(int4*)(As + rr * 72 + l8 * 8) = av[rI];
            *(int4*)(Bs + rr * 72 + l8 * 8) = bv[rI];
        }
        __syncthreads();
        #pragma unroll
        for (int kk = 0; kk < 2; ++kk) {
            bf16x8 af[4], bf[4];
            #pragma unroll
            for (int mi = 0; mi < 4; ++mi)
                af[mi] = *(const bf16x8*)(As + (wr * 64 + mi * 16 + (l & 15)) * 72 + kk * 32 + (l >> 4) * 8);
            #pragma unroll
            for (int ni = 0; ni < 4; ++ni)
                bf[ni] = *(const bf16x8*)(Bs + (wc * 64 + ni * 16 + (l & 15)) * 72 + kk * 32 + (l >> 4) * 8);
            #pragma unroll
            for (int mi = 0; mi < 4; ++mi)
                #pragma unroll
                for (int ni = 0; ni < 4; ++ni)
                    acc[mi][ni] = __builtin_amdgcn_mfma_f32_16x16x32_bf16(af[mi], bf[ni], acc[mi][ni], 0, 0, 0);
        }
    }
    // epilogue: + bh, scatter to out[b][t][col]
    #pragma unroll
    for (int ni = 0; ni < 4; ++ni) {
        int col = n0 + wc * 64 + ni * 16 + (l & 15);
        float bhv = bh[col];
        #pragma unroll
        for (int mi = 0; mi < 4; ++mi) {
            #pragma unroll
            for (int e = 0; e < 4; ++e) {
                int gr = row0 + wr * 64 + mi * 16 + (l >> 4) * 4 + e; // chunk-local (t,b) row
                int t = t0 + (gr >> 6), b = gr & 63;
                out[((size_t)b * T_SEQ + t) * HID + col] = acc[mi][ni][e] + bhv;
            }
        }
    }
}

// ---------------- K4: h recurrence, in place on d_out ----------------
__global__ __launch_bounds__(256, 1) void k4_hrec(
        const unsigned short* __restrict__ Uhb,
        float* __restrict__ out, int* __restrict__ flags) {
    __shared__ short UhT[64 * 520];   // [64 cols][512 k] bf16, padded
    __shared__ short hp[16 * 520];    // [16 batch][512 k] bf16, padded
    const int tid = threadIdx.x;
    const int l = tid & 63, w = tid >> 6;
    const int g = blockIdx.x >> 3, s = blockIdx.x & 7;
    const int c0 = s * 64;

    for (int rp = 0; rp < 128; ++rp) {
        int idx = rp * 256 + tid;
        int j = idx & 63, k = idx >> 6;
        UhT[j * 520 + k] = (short)Uhb[(size_t)k * HID + c0 + j];
    }
    __syncthreads();

    const int bi = tid >> 4, part = tid & 15;
    const int colL = w * 16 + (l & 15);
    const int col = c0 + colL;

    for (int t = 0; t < T_SEQ; ++t) {
        f32x4 acc = {0.f, 0.f, 0.f, 0.f};
        if (t > 0) {
            if (tid == 0) {
                while (__hip_atomic_load(&flags[(t - 1) * 4 + g],
                                         __ATOMIC_ACQUIRE, __HIP_MEMORY_SCOPE_AGENT) < 8) {}
            }
            __syncthreads();
            __threadfence();
            // stage h_{t-1} (f32 from out) -> bf16 LDS
            const float4* src = (const float4*)(out + ((size_t)(g * 16 + bi) * T_SEQ + (t - 1)) * HID + part * 32);
            #pragma unroll
            for (int q = 0; q < 8; ++q) {
                float4 v = src[q];
                ushort4 pk;
                pk.x = f2bf(v.x); pk.y = f2bf(v.y); pk.z = f2bf(v.z); pk.w = f2bf(v.w);
                *(ushort4*)(hp + bi * 520 + part * 32 + q * 4) = pk;
            }
            __syncthreads();
            #pragma unroll
            for (int kk = 0; kk < 16; ++kk) {
                bf16x8 a = *(const bf16x8*)(hp + (l & 15) * 520 + kk * 32 + (l >> 4) * 8);
                bf16x8 bb = *(const bf16x8*)(UhT + colL * 520 + kk * 32 + (l >> 4) * 8);
                acc = __builtin_amdgcn_mfma_f32_16x16x32_bf16(a, bb, acc, 0, 0, 0);
            }
        }
        #pragma unroll
        for (int e = 0; e < 4; ++e) {
            int brow = g * 16 + (l >> 4) * 4 + e;
            size_t oidx = ((size_t)brow * T_SEQ + t) * HID + col;
            out[oidx] = tanhf(out[oidx] + acc[e]);
        }
        __threadfence();
        __syncthreads();
        if (tid == 0)
            __hip_atomic_fetch_add(&flags[t * 4 + g], 1,
                                   __ATOMIC_RELEASE, __HIP_MEMORY_SCOPE_AGENT);
    }
}

// ---------------- host ----------------
extern "C" void kernel_launch(void* const* d_in, const int* in_sizes, int n_in,
                              void* d_out, int out_size, void* d_ws, size_t ws_size,
                              hipStream_t stream) {
    const float* x    = (const float*)d_in[0];
    const float* kern = (const float*)d_in[1];
    const float* A    = (const float*)d_in[2];
    const float* Bv   = (const float*)d_in[3];
    const float* Wh   = (const float*)d_in[4];
    const float* Uh   = (const float*)d_in[5];
    const float* bh   = (const float*)d_in[6];
    float* out = (float*)d_out;

    char* ws = (char*)d_ws;
    size_t off = 0;
    auto walloc = [&](size_t bytes) {
        void* p = ws + off;
        off += (bytes + 255) & ~(size_t)255;
        return p;
    };
    float* u             = (float*)walloc(sizeof(float) * NROWS * T_SEQ);        // 8 MB
    float* m_state       = (float*)walloc(sizeof(float) * NROWS * 64);           // 512 KB
    unsigned short* Wh2T = (unsigned short*)walloc(sizeof(short) * HID * KDIM);  // 4 MB
    unsigned short* Uhb  = (unsigned short*)walloc(sizeof(short) * HID * HID);   // 512 KB
    int* flags           = (int*)walloc(sizeof(int) * T_SEQ * 4);                // 16 KB
    unsigned short* m_ch = (unsigned short*)walloc(sizeof(short) * (size_t)TCH * 64 * KDIM); // 64 MB
    (void)ws_size; (void)in_sizes; (void)n_in; (void)out_size;

    hipMemsetAsync(flags, 0, sizeof(int) * T_SEQ * 4, stream);
    k0_convert<<<2048, 256, 0, stream>>>(Wh, Uh, Wh2T, Uhb);
    k1_ugemm<<<1024, 256, 0, stream>>>(x, kern, u);
    for (int c = 0; c < NCHUNK; ++c) {
        k2_mscan<<<256, 256, 0, stream>>>(u, A, Bv, m_state, m_ch, c * TCH);
        dim3 g3(64, 4);
        k3_gemm<<<g3, 256, 0, stream>>>(m_ch, Wh2T, bh, out, c * TCH);
    }
    k4_hrec<<<32, 256, 0, stream>>>(Uhb, out, flags);
}

// Round 4
// 11504.166 us; speedup vs baseline: 1.0125x; 1.0125x over previous
//
#include <hip/hip_runtime.h>
#include <hip/hip_bf16.h>

// LMU cell, MI355X. Phases:
//  K0: convert Wh -> Wh2T (bf16, [512 n][4096 k], Wh stacked twice for hi/lo m split),
//      Uh -> bf16.
//  K1: u[bm][t] = x@kernel  (f32)
//  K2: sequential m-scan over t (f32 state in LDS, A columns in VGPRs),
//      writes m as bf16 hi/lo into chunk buffer [128*64 rows][4096]
//  K3: pre = m@Wh + bh as bf16 MFMA GEMM (K=4096), writes pre INTO d_out[b][t][h]
//  K4: h_t = tanh(pre_t + h_{t-1}@Uh): 32 blocks = 4 batch-groups x 8 hidden-slices,
//      Uh^T slice in LDS, per-step 8-block spin barrier (cache-line-padded flags,
//      s_sleep backoff), h exchanged as bf16 via small double buffer hxch,
//      pre read/overwritten in place on d_out.

#define T_SEQ 1024
#define BATCHN 64
#define MEMD 32
#define ORD 64
#define HID 512
#define DIN 128
#define NROWS 2048            // BATCHN*MEMD
#define KDIM 4096             // 2*MEMD*ORD (hi | lo)
#define TCH 128
#define NCHUNK 8
#define PITCH 520             // LDS row pitch (shorts)
#define FSTRIDE 32            // ints per flag slot (128 B -> one cache line per group)

typedef __attribute__((ext_vector_type(4))) float f32x4;
typedef __attribute__((ext_vector_type(8))) __bf16 bf16x8;

static __device__ __forceinline__ unsigned short f2bf(float f) {
    __hip_bfloat16 h = __float2bfloat16(f);
    return *reinterpret_cast<unsigned short*>(&h);
}
static __device__ __forceinline__ float bf2f(unsigned short s) {
    __hip_bfloat16 h = *reinterpret_cast<__hip_bfloat16*>(&s);
    return __bfloat162float(h);
}

// ---------------- K0: weight conversion ----------------
__global__ __launch_bounds__(256) void k0_convert(
        const float* __restrict__ Wh, const float* __restrict__ Uh,
        unsigned short* __restrict__ Wh2T, unsigned short* __restrict__ Uhb) {
    const int total = HID * KDIM + HID * HID;
    for (int idx = blockIdx.x * 256 + threadIdx.x; idx < total; idx += gridDim.x * 256) {
        if (idx < HID * KDIM) {
            int n = idx >> 12;          // /4096
            int k = idx & 4095;
            int ks = (k >= 2048) ? (k - 2048) : k;   // Wh stacked twice
            Wh2T[idx] = f2bf(Wh[(size_t)ks * HID + n]);
        } else {
            int j = idx - HID * KDIM;
            Uhb[j] = f2bf(Uh[j]);
        }
    }
}

// ---------------- K1: u = x @ kernel -> u[bm][t] ----------------
__global__ __launch_bounds__(256) void k1_ugemm(
        const float* __restrict__ x, const float* __restrict__ kern,
        float* __restrict__ u) {
    __shared__ float xs[64 * 128];
    __shared__ float kT[32 * 129];
    const int b = blockIdx.x >> 4;
    const int tt = blockIdx.x & 15;
    const int t0 = tt * 64;
    const int tid = threadIdx.x;

    const float4* xg = reinterpret_cast<const float4*>(x + ((size_t)b * T_SEQ + t0) * DIN);
    float4* xs4 = reinterpret_cast<float4*>(xs);
    #pragma unroll
    for (int r = 0; r < 8; ++r) xs4[r * 256 + tid] = xg[r * 256 + tid];
    #pragma unroll
    for (int r = 0; r < 16; ++r) {
        int idx = r * 256 + tid;        // 4096 = 128 d * 32 m
        int d = idx >> 5, m = idx & 31;
        kT[m * 129 + d] = kern[idx];
    }
    __syncthreads();

    const int m = tid & 31, tq = tid >> 5;
    float acc[8];
    #pragma unroll
    for (int i = 0; i < 8; ++i) acc[i] = 0.f;
    #pragma unroll
    for (int d4 = 0; d4 < 32; ++d4) {
        float k0 = kT[m * 129 + d4 * 4 + 0];
        float k1 = kT[m * 129 + d4 * 4 + 1];
        float k2 = kT[m * 129 + d4 * 4 + 2];
        float k3 = kT[m * 129 + d4 * 4 + 3];
        #pragma unroll
        for (int i = 0; i < 8; ++i) {
            float4 xv = xs4[(tq * 8 + i) * 32 + d4];
            acc[i] += xv.x * k0 + xv.y * k1 + xv.z * k2 + xv.w * k3;
        }
    }
    #pragma unroll
    for (int i = 0; i < 8; ++i)
        u[((size_t)(b * MEMD + m)) * T_SEQ + t0 + tq * 8 + i] = acc[i];
}

// ---------------- K2: m-scan (f32), writes bf16 hi/lo ----------------
__global__ __launch_bounds__(256, 1) void k2_mscan(
        const float* __restrict__ u, const float* __restrict__ A,
        const float* __restrict__ Bv, float* __restrict__ m_state,
        unsigned short* __restrict__ m_buf, int t0) {
    __shared__ float mbuf[2][8][64];
    __shared__ float ul[8][128];
    const int tid = threadIdx.x;
    const int wv = tid >> 6, half = (tid >> 5) & 1, pl = tid & 31;
    const int rl = wv * 2 + half;           // local row 0..7
    const int r = blockIdx.x * 8 + rl;      // global row (b*32+mem)
    const int p0 = pl * 2;

    float A0[64], A1[64];
    #pragma unroll
    for (int o = 0; o < 64; ++o) {
        A0[o] = A[o * 64 + p0];
        A1[o] = A[o * 64 + p0 + 1];
    }
    const float B0 = Bv[p0], B1 = Bv[p0 + 1];

    {   // stage u chunk: [8 rows][128 t]
        int row = tid >> 5, c4 = (tid & 31) * 4;
        *(float4*)&ul[row][c4] =
            *(const float4*)&u[(size_t)(blockIdx.x * 8 + row) * T_SEQ + t0 + c4];
    }
    float mc0, mc1;
    if (t0 == 0) { mc0 = 0.f; mc1 = 0.f; }
    else { mc0 = m_state[r * 64 + p0]; mc1 = m_state[r * 64 + p0 + 1]; }
    mbuf[0][rl][p0] = mc0;
    mbuf[0][rl][p0 + 1] = mc1;
    __syncthreads();

    const int b = r >> 5, mem = r & 31;
    int cur = 0;
    for (int tl = 0; tl < TCH; ++tl) {
        const float ut = ul[rl][tl];
        float a0 = ut * B0, a1 = ut * B1;
        const float4* mrow = (const float4*)&mbuf[cur][rl][0];
        #pragma unroll
        for (int o4 = 0; o4 < 16; ++o4) {
            float4 mv = mrow[o4];
            a0 += mv.x * A0[o4 * 4] + mv.y * A0[o4 * 4 + 1] + mv.z * A0[o4 * 4 + 2] + mv.w * A0[o4 * 4 + 3];
            a1 += mv.x * A1[o4 * 4] + mv.y * A1[o4 * 4 + 1] + mv.z * A1[o4 * 4 + 2] + mv.w * A1[o4 * 4 + 3];
        }
        size_t rowg = (size_t)(tl * 64 + b) * KDIM + mem * 64 + p0;
        unsigned short h0 = f2bf(a0), h1 = f2bf(a1);
        float f0 = a0 - bf2f(h0);
        float f1 = a1 - bf2f(h1);
        ushort2 hv; hv.x = h0; hv.y = h1;
        ushort2 lv; lv.x = f2bf(f0); lv.y = f2bf(f1);
        *(ushort2*)&m_buf[rowg] = hv;
        *(ushort2*)&m_buf[rowg + 2048] = lv;
        mbuf[cur ^ 1][rl][p0] = a0;
        mbuf[cur ^ 1][rl][p0 + 1] = a1;
        mc0 = a0; mc1 = a1;
        cur ^= 1;
        __syncthreads();
    }
    m_state[r * 64 + p0] = mc0;
    m_state[r * 64 + p0 + 1] = mc1;
}

// ---------------- K3: pre = m @ Wh + bh  (bf16 MFMA, K=4096) ----------------
__global__ __launch_bounds__(256, 1) void k3_gemm(
        const unsigned short* __restrict__ m_chunk,
        const unsigned short* __restrict__ Wh2T,
        const float* __restrict__ bh,
        float* __restrict__ out, int t0) {
    __shared__ short As[128 * 72];
    __shared__ short Bs[128 * 72];
    const int tid = threadIdx.x;
    const int l = tid & 63, wv = tid >> 6;
    const int wr = wv >> 1, wc = wv & 1;
    const int row0 = blockIdx.x * 128, n0 = blockIdx.y * 128;

    f32x4 acc[4][4];
    #pragma unroll
    for (int i = 0; i < 4; ++i)
        #pragma unroll
        for (int j = 0; j < 4; ++j)
            acc[i][j] = (f32x4){0.f, 0.f, 0.f, 0.f};

    for (int k0 = 0; k0 < KDIM; k0 += 64) {
        int4 av[4], bv[4];
        #pragma unroll
        for (int rI = 0; rI < 4; ++rI) {
            int idx = rI * 256 + tid;
            int rr = idx >> 3, l8 = idx & 7;
            av[rI] = *(const int4*)(m_chunk + (size_t)(row0 + rr) * KDIM + k0 + l8 * 8);
            bv[rI] = *(const int4*)(Wh2T + (size_t)(n0 + rr) * KDIM + k0 + l8 * 8);
        }
        __syncthreads();
        #pragma unroll
        for (int rI = 0; rI < 4; ++rI) {
            int idx = rI * 256 + tid;
            int rr = idx >> 3, l8 = idx & 7;
            *(int4*)(As + rr * 72 + l8 * 8) = av[rI];
            *(int4*)(Bs + rr * 72 + l8 * 8) = bv[rI];
        }
        __syncthreads();
        #pragma unroll
        for (int kk = 0; kk < 2; ++kk) {
            bf16x8 af[4], bf[4];
            #pragma unroll
            for (int mi = 0; mi < 4; ++mi)
                af[mi] = *(const bf16x8*)(As + (wr * 64 + mi * 16 + (l & 15)) * 72 + kk * 32 + (l >> 4) * 8);
            #pragma unroll
            for (int ni = 0; ni < 4; ++ni)
                bf[ni] = *(const bf16x8*)(Bs + (wc * 64 + ni * 16 + (l & 15)) * 72 + kk * 32 + (l >> 4) * 8);
            #pragma unroll
            for (int mi = 0; mi < 4; ++mi)
                #pragma unroll
                for (int ni = 0; ni < 4; ++ni)
                    acc[mi][ni] = __builtin_amdgcn_mfma_f32_16x16x32_bf16(af[mi], bf[ni], acc[mi][ni], 0, 0, 0);
        }
    }
    #pragma unroll
    for (int ni = 0; ni < 4; ++ni) {
        int col = n0 + wc * 64 + ni * 16 + (l & 15);
        float bhv = bh[col];
        #pragma unroll
        for (int mi = 0; mi < 4; ++mi) {
            #pragma unroll
            for (int e = 0; e < 4; ++e) {
                int gr = row0 + wr * 64 + mi * 16 + (l >> 4) * 4 + e; // chunk-local (t,b) row
                int t = t0 + (gr >> 6), b = gr & 63;
                out[((size_t)b * T_SEQ + t) * HID + col] = acc[mi][ni][e] + bhv;
            }
        }
    }
}

// ---------------- K4: h recurrence, round-1 structure ----------------
// 32 blocks x 256 thr. group g = blockIdx>>3 (16 batches), slice s = blockIdx&7
// (64 cols). Uh^T slice staged once in LDS; per-step 8-block spin barrier on
// cache-line-padded flags with s_sleep backoff; h exchanged bf16 via
// hxch[2][64][512]; pre read/overwritten in place on d_out.
__global__ __launch_bounds__(256, 1) void k4_hrec(
        const unsigned short* __restrict__ Uhb,
        float* __restrict__ out,
        unsigned short* __restrict__ hxch,
        int* __restrict__ flags) {
    __shared__ short UhT[64 * PITCH];   // 66,560 B
    __shared__ short hp[16 * PITCH];    // 16,640 B
    const int tid = threadIdx.x;
    const int l = tid & 63, w = tid >> 6;
    const int g = blockIdx.x >> 3, s = blockIdx.x & 7;
    const int b0 = g * 16;
    const int c0 = s * 64;

    // stage Uh col-slice -> LDS transposed [colLocal][k]
    for (int rp = 0; rp < 128; ++rp) {
        int idx = rp * 256 + tid;       // 32768 = 512 k * 64 col
        int j = idx & 63, k = idx >> 6;
        UhT[j * PITCH + k] = (short)Uhb[(size_t)k * HID + c0 + j];
    }
    __syncthreads();

    const int colL = w * 16 + (l & 15);
    const int col = c0 + colL;

    for (int t = 0; t < T_SEQ; ++t) {
        f32x4 acc = {0.f, 0.f, 0.f, 0.f};
        if (t > 0) {
            if (tid == 0) {
                while (__hip_atomic_load(&flags[((t - 1) * 4 + g) * FSTRIDE],
                                         __ATOMIC_ACQUIRE, __HIP_MEMORY_SCOPE_AGENT) < 8)
                    __builtin_amdgcn_s_sleep(4);
            }
            __syncthreads();
            __threadfence();
            {   // stage h_{t-1} bf16 [16 batch][512] -> hp
                const int bb = tid >> 4;            // 0..15
                const int k0 = (tid & 15) * 32;     // 0..480
                const unsigned short* src =
                    hxch + ((size_t)(((t - 1) & 1) * 64 + b0 + bb) << 9) + k0;
                int4 v0 = *(const int4*)(src);
                int4 v1 = *(const int4*)(src + 8);
                int4 v2 = *(const int4*)(src + 16);
                int4 v3 = *(const int4*)(src + 24);
                *(int4*)(hp + bb * PITCH + k0)      = v0;
                *(int4*)(hp + bb * PITCH + k0 + 8)  = v1;
                *(int4*)(hp + bb * PITCH + k0 + 16) = v2;
                *(int4*)(hp + bb * PITCH + k0 + 24) = v3;
            }
            __syncthreads();
            #pragma unroll
            for (int kk = 0; kk < 16; ++kk) {
                bf16x8 a  = *(const bf16x8*)(hp  + (l & 15) * PITCH + kk * 32 + (l >> 4) * 8);
                bf16x8 bb = *(const bf16x8*)(UhT + colL     * PITCH + kk * 32 + (l >> 4) * 8);
                acc = __builtin_amdgcn_mfma_f32_16x16x32_bf16(a, bb, acc, 0, 0, 0);
            }
        }
        #pragma unroll
        for (int e = 0; e < 4; ++e) {
            int brow = b0 + (l >> 4) * 4 + e;
            size_t oidx = ((size_t)brow * T_SEQ + t) * HID + col;
            float hv = tanhf(out[oidx] + acc[e]);
            out[oidx] = hv;
            hxch[((size_t)((t & 1) * 64 + brow) << 9) + col] = f2bf(hv);
        }
        __threadfence();
        __syncthreads();
        if (tid == 0)
            __hip_atomic_fetch_add(&flags[(t * 4 + g) * FSTRIDE], 1,
                                   __ATOMIC_RELEASE, __HIP_MEMORY_SCOPE_AGENT);
    }
}

// ---------------- host ----------------
extern "C" void kernel_launch(void* const* d_in, const int* in_sizes, int n_in,
                              void* d_out, int out_size, void* d_ws, size_t ws_size,
                              hipStream_t stream) {
    const float* x    = (const float*)d_in[0];
    const float* kern = (const float*)d_in[1];
    const float* A    = (const float*)d_in[2];
    const float* Bv   = (const float*)d_in[3];
    const float* Wh   = (const float*)d_in[4];
    const float* Uh   = (const float*)d_in[5];
    const float* bh   = (const float*)d_in[6];
    float* out = (float*)d_out;

    char* ws = (char*)d_ws;
    size_t off = 0;
    auto walloc = [&](size_t bytes) {
        void* p = ws + off;
        off += (bytes + 255) & ~(size_t)255;
        return p;
    };
    float* u             = (float*)walloc(sizeof(float) * NROWS * T_SEQ);        // 8 MB
    float* m_state       = (float*)walloc(sizeof(float) * NROWS * 64);           // 512 KB
    unsigned short* Wh2T = (unsigned short*)walloc(sizeof(short) * HID * KDIM);  // 4 MB
    unsigned short* Uhb  = (unsigned short*)walloc(sizeof(short) * HID * HID);   // 512 KB
    int* flags           = (int*)walloc(sizeof(int) * T_SEQ * 4 * FSTRIDE);      // 512 KB
    unsigned short* hxch = (unsigned short*)walloc(sizeof(short) * 2 * BATCHN * HID); // 128 KB
    unsigned short* m_ch = (unsigned short*)walloc(sizeof(short) * (size_t)TCH * 64 * KDIM); // 64 MB
    (void)ws_size; (void)in_sizes; (void)n_in; (void)out_size;

    hipMemsetAsync(flags, 0, sizeof(int) * T_SEQ * 4 * FSTRIDE, stream);
    k0_convert<<<2048, 256, 0, stream>>>(Wh, Uh, Wh2T, Uhb);
    k1_ugemm<<<1024, 256, 0, stream>>>(x, kern, u);
    for (int c = 0; c < NCHUNK; ++c) {
        k2_mscan<<<256, 256, 0, stream>>>(u, A, Bv, m_state, m_ch, c * TCH);
        dim3 g3(64, 4);
        k3_gemm<<<g3, 256, 0, stream>>>(m_ch, Wh2T, bh, out, c * TCH);
    }
    k4_hrec<<<32, 256, 0, stream>>>(Uhb, out, hxch, flags);
}

// Round 5
// 7750.616 us; speedup vs baseline: 1.5029x; 1.4843x over previous
//
#include <hip/hip_runtime.h>
#include <hip/hip_bf16.h>

// LMU cell, MI355X. Phases:
//  K0: convert Wh -> Wh2T (bf16, [512 n][4096 k], Wh stacked twice for hi/lo m split),
//      Uh -> UhbT (bf16, transposed [col][k]).
//  K1: u[bm][t] = x@kernel  (f32)
//  K2: sequential m-scan over t (f32 state in LDS, A columns in VGPRs),
//      writes m as bf16 hi/lo into chunk buffer [128*64 rows][4096]
//  K3: pre = m@Wh + bh as bf16 MFMA GEMM (K=4096), writes pre INTO d_out[b][t][h]
//  K4: h_t = tanh(pre_t + h_{t-1}@Uh), BATCH-SPLIT: 4 blocks x 16 batches,
//      each block computes the FULL 512-wide h for its batches -> the
//      recurrence is self-contained per block. NO inter-block sync, no
//      fences, no atomics. Uh (512 KB bf16) streamed from L2 every step;
//      h double-buffered in LDS (one __syncthreads per step).

#define T_SEQ 1024
#define BATCHN 64
#define MEMD 32
#define ORD 64
#define HID 512
#define DIN 128
#define NROWS 2048            // BATCHN*MEMD
#define KDIM 4096             // 2*MEMD*ORD (hi | lo)
#define TCH 128
#define NCHUNK 8
#define PITCH 520             // LDS row pitch (shorts) for [16][512] bf16 tile

typedef __attribute__((ext_vector_type(4))) float f32x4;
typedef __attribute__((ext_vector_type(8))) __bf16 bf16x8;

static __device__ __forceinline__ unsigned short f2bf(float f) {
    __hip_bfloat16 h = __float2bfloat16(f);
    return *reinterpret_cast<unsigned short*>(&h);
}
static __device__ __forceinline__ float bf2f(unsigned short s) {
    __hip_bfloat16 h = *reinterpret_cast<__hip_bfloat16*>(&s);
    return __bfloat162float(h);
}

// ---------------- K0: weight conversion ----------------
__global__ __launch_bounds__(256) void k0_convert(
        const float* __restrict__ Wh, const float* __restrict__ Uh,
        unsigned short* __restrict__ Wh2T, unsigned short* __restrict__ UhbT) {
    const int total = HID * KDIM + HID * HID;
    for (int idx = blockIdx.x * 256 + threadIdx.x; idx < total; idx += gridDim.x * 256) {
        if (idx < HID * KDIM) {
            int n = idx >> 12;          // /4096
            int k = idx & 4095;
            int ks = (k >= 2048) ? (k - 2048) : k;   // Wh stacked twice
            Wh2T[idx] = f2bf(Wh[(size_t)ks * HID + n]);
        } else {
            int j = idx - HID * KDIM;   // j = col*512 + k
            int col = j >> 9, k = j & 511;
            UhbT[j] = f2bf(Uh[(size_t)k * HID + col]);
        }
    }
}

// ---------------- K1: u = x @ kernel -> u[bm][t] ----------------
__global__ __launch_bounds__(256) void k1_ugemm(
        const float* __restrict__ x, const float* __restrict__ kern,
        float* __restrict__ u) {
    __shared__ float xs[64 * 128];
    __shared__ float kT[32 * 129];
    const int b = blockIdx.x >> 4;
    const int tt = blockIdx.x & 15;
    const int t0 = tt * 64;
    const int tid = threadIdx.x;

    const float4* xg = reinterpret_cast<const float4*>(x + ((size_t)b * T_SEQ + t0) * DIN);
    float4* xs4 = reinterpret_cast<float4*>(xs);
    #pragma unroll
    for (int r = 0; r < 8; ++r) xs4[r * 256 + tid] = xg[r * 256 + tid];
    #pragma unroll
    for (int r = 0; r < 16; ++r) {
        int idx = r * 256 + tid;        // 4096 = 128 d * 32 m
        int d = idx >> 5, m = idx & 31;
        kT[m * 129 + d] = kern[idx];
    }
    __syncthreads();

    const int m = tid & 31, tq = tid >> 5;
    float acc[8];
    #pragma unroll
    for (int i = 0; i < 8; ++i) acc[i] = 0.f;
    #pragma unroll
    for (int d4 = 0; d4 < 32; ++d4) {
        float k0 = kT[m * 129 + d4 * 4 + 0];
        float k1 = kT[m * 129 + d4 * 4 + 1];
        float k2 = kT[m * 129 + d4 * 4 + 2];
        float k3 = kT[m * 129 + d4 * 4 + 3];
        #pragma unroll
        for (int i = 0; i < 8; ++i) {
            float4 xv = xs4[(tq * 8 + i) * 32 + d4];
            acc[i] += xv.x * k0 + xv.y * k1 + xv.z * k2 + xv.w * k3;
        }
    }
    #pragma unroll
    for (int i = 0; i < 8; ++i)
        u[((size_t)(b * MEMD + m)) * T_SEQ + t0 + tq * 8 + i] = acc[i];
}

// ---------------- K2: m-scan (f32), writes bf16 hi/lo ----------------
__global__ __launch_bounds__(256, 1) void k2_mscan(
        const float* __restrict__ u, const float* __restrict__ A,
        const float* __restrict__ Bv, float* __restrict__ m_state,
        unsigned short* __restrict__ m_buf, int t0) {
    __shared__ float mbuf[2][8][64];
    __shared__ float ul[8][128];
    const int tid = threadIdx.x;
    const int wv = tid >> 6, half = (tid >> 5) & 1, pl = tid & 31;
    const int rl = wv * 2 + half;           // local row 0..7
    const int r = blockIdx.x * 8 + rl;      // global row (b*32+mem)
    const int p0 = pl * 2;

    float A0[64], A1[64];
    #pragma unroll
    for (int o = 0; o < 64; ++o) {
        A0[o] = A[o * 64 + p0];
        A1[o] = A[o * 64 + p0 + 1];
    }
    const float B0 = Bv[p0], B1 = Bv[p0 + 1];

    {   // stage u chunk: [8 rows][128 t]
        int row = tid >> 5, c4 = (tid & 31) * 4;
        *(float4*)&ul[row][c4] =
            *(const float4*)&u[(size_t)(blockIdx.x * 8 + row) * T_SEQ + t0 + c4];
    }
    float mc0, mc1;
    if (t0 == 0) { mc0 = 0.f; mc1 = 0.f; }
    else { mc0 = m_state[r * 64 + p0]; mc1 = m_state[r * 64 + p0 + 1]; }
    mbuf[0][rl][p0] = mc0;
    mbuf[0][rl][p0 + 1] = mc1;
    __syncthreads();

    const int b = r >> 5, mem = r & 31;
    int cur = 0;
    for (int tl = 0; tl < TCH; ++tl) {
        const float ut = ul[rl][tl];
        float a0 = ut * B0, a1 = ut * B1;
        const float4* mrow = (const float4*)&mbuf[cur][rl][0];
        #pragma unroll
        for (int o4 = 0; o4 < 16; ++o4) {
            float4 mv = mrow[o4];
            a0 += mv.x * A0[o4 * 4] + mv.y * A0[o4 * 4 + 1] + mv.z * A0[o4 * 4 + 2] + mv.w * A0[o4 * 4 + 3];
            a1 += mv.x * A1[o4 * 4] + mv.y * A1[o4 * 4 + 1] + mv.z * A1[o4 * 4 + 2] + mv.w * A1[o4 * 4 + 3];
        }
        size_t rowg = (size_t)(tl * 64 + b) * KDIM + mem * 64 + p0;
        unsigned short h0 = f2bf(a0), h1 = f2bf(a1);
        float f0 = a0 - bf2f(h0);
        float f1 = a1 - bf2f(h1);
        ushort2 hv; hv.x = h0; hv.y = h1;
        ushort2 lv; lv.x = f2bf(f0); lv.y = f2bf(f1);
        *(ushort2*)&m_buf[rowg] = hv;
        *(ushort2*)&m_buf[rowg + 2048] = lv;
        mbuf[cur ^ 1][rl][p0] = a0;
        mbuf[cur ^ 1][rl][p0 + 1] = a1;
        mc0 = a0; mc1 = a1;
        cur ^= 1;
        __syncthreads();
    }
    m_state[r * 64 + p0] = mc0;
    m_state[r * 64 + p0 + 1] = mc1;
}

// ---------------- K3: pre = m @ Wh + bh  (bf16 MFMA, K=4096) ----------------
__global__ __launch_bounds__(256, 1) void k3_gemm(
        const unsigned short* __restrict__ m_chunk,
        const unsigned short* __restrict__ Wh2T,
        const float* __restrict__ bh,
        float* __restrict__ out, int t0) {
    __shared__ short As[128 * 72];
    __shared__ short Bs[128 * 72];
    const int tid = threadIdx.x;
    const int l = tid & 63, wv = tid >> 6;
    const int wr = wv >> 1, wc = wv & 1;
    const int row0 = blockIdx.x * 128, n0 = blockIdx.y * 128;

    f32x4 acc[4][4];
    #pragma unroll
    for (int i = 0; i < 4; ++i)
        #pragma unroll
        for (int j = 0; j < 4; ++j)
            acc[i][j] = (f32x4){0.f, 0.f, 0.f, 0.f};

    for (int k0 = 0; k0 < KDIM; k0 += 64) {
        int4 av[4], bv[4];
        #pragma unroll
        for (int rI = 0; rI < 4; ++rI) {
            int idx = rI * 256 + tid;
            int rr = idx >> 3, l8 = idx & 7;
            av[rI] = *(const int4*)(m_chunk + (size_t)(row0 + rr) * KDIM + k0 + l8 * 8);
            bv[rI] = *(const int4*)(Wh2T + (size_t)(n0 + rr) * KDIM + k0 + l8 * 8);
        }
        __syncthreads();
        #pragma unroll
        for (int rI = 0; rI < 4; ++rI) {
            int idx = rI * 256 + tid;
            int rr = idx >> 3, l8 = idx & 7;
            *(int4*)(As + rr * 72 + l8 * 8) = av[rI];
            *(int4*)(Bs + rr * 72 + l8 * 8) = bv[rI];
        }
        __syncthreads();
        #pragma unroll
        for (int kk = 0; kk < 2; ++kk) {
            bf16x8 af[4], bf[4];
            #pragma unroll
            for (int mi = 0; mi < 4; ++mi)
                af[mi] = *(const bf16x8*)(As + (wr * 64 + mi * 16 + (l & 15)) * 72 + kk * 32 + (l >> 4) * 8);
            #pragma unroll
            for (int ni = 0; ni < 4; ++ni)
                bf[ni] = *(const bf16x8*)(Bs + (wc * 64 + ni * 16 + (l & 15)) * 72 + kk * 32 + (l >> 4) * 8);
            #pragma unroll
            for (int mi = 0; mi < 4; ++mi)
                #pragma unroll
                for (int ni = 0; ni < 4; ++ni)
                    acc[mi][ni] = __builtin_amdgcn_mfma_f32_16x16x32_bf16(af[mi], bf[ni], acc[mi][ni], 0, 0, 0);
        }
    }
    #pragma unroll
    for (int ni = 0; ni < 4; ++ni) {
        int col = n0 + wc * 64 + ni * 16 + (l & 15);
        float bhv = bh[col];
        #pragma unroll
        for (int mi = 0; mi < 4; ++mi) {
            #pragma unroll
            for (int e = 0; e < 4; ++e) {
                int gr = row0 + wr * 64 + mi * 16 + (l >> 4) * 4 + e; // chunk-local (t,b) row
                int t = t0 + (gr >> 6), b = gr & 63;
                out[((size_t)b * T_SEQ + t) * HID + col] = acc[mi][ni][e] + bhv;
            }
        }
    }
}

// ---------------- K4: h recurrence, batch-split, zero inter-block sync ----
// 4 blocks x 512 thr (8 waves). Block bg owns batches bg*16..+15 and computes
// the FULL 512-wide h each step. Wave w owns output cols [w*64, w*64+64).
// Uh streamed from L2 (UhbT [col][k], 512 KB, L2-resident after step 1).
// h double-buffered in LDS -> one __syncthreads per step.
__global__ __launch_bounds__(512, 2) void k4_hrec(
        const unsigned short* __restrict__ UhbT,
        float* __restrict__ out) {
    __shared__ short hlds[2][16 * PITCH];   // 33,280 B
    const int tid = threadIdx.x;
    const int l = tid & 63, w = tid >> 6;   // wave 0..7
    const int bg = blockIdx.x;              // 0..3
    const int b0 = bg * 16;
    const int lr = l & 15, lq = l >> 4;     // frag row / k-quad
    const int colBase = w * 64;

    // per-lane B-operand base pointers (col-major UhbT: [col][512 k])
    const unsigned short* ub[4];
    #pragma unroll
    for (int nt = 0; nt < 4; ++nt)
        ub[nt] = UhbT + ((size_t)(colBase + nt * 16 + lr) << 9) + lq * 8;

    for (int t = 0; t < T_SEQ; ++t) {
        // pre_t for this lane's 16 output slots (issued early, used post-MFMA)
        float pv[4][4];
        #pragma unroll
        for (int nt = 0; nt < 4; ++nt)
            #pragma unroll
            for (int e = 0; e < 4; ++e)
                pv[nt][e] = out[((size_t)(b0 + lq * 4 + e) * T_SEQ + t) * HID
                                + colBase + nt * 16 + lr];

        f32x4 acc[4];
        #pragma unroll
        for (int nt = 0; nt < 4; ++nt) acc[nt] = (f32x4){0.f, 0.f, 0.f, 0.f};

        if (t > 0) {
            const short* hread = hlds[(t + 1) & 1];   // h_{t-1}
            #pragma unroll
            for (int kt = 0; kt < 16; ++kt) {
                bf16x8 a = *(const bf16x8*)(hread + lr * PITCH + kt * 32 + lq * 8);
                #pragma unroll
                for (int nt = 0; nt < 4; ++nt) {
                    bf16x8 b = *(const bf16x8*)(ub[nt] + kt * 32);
                    acc[nt] = __builtin_amdgcn_mfma_f32_16x16x32_bf16(a, b, acc[nt], 0, 0, 0);
                }
            }
        }
        // write h_t into the OTHER buffer (no pre-write barrier needed)
        short* hwrite = hlds[t & 1];
        #pragma unroll
        for (int nt = 0; nt < 4; ++nt) {
            const int col = colBase + nt * 16 + lr;
            #pragma unroll
            for (int e = 0; e < 4; ++e) {
                const int row = lq * 4 + e;
                float hv = tanhf(pv[nt][e] + acc[nt][e]);
                out[((size_t)(b0 + row) * T_SEQ + t) * HID + col] = hv;
                hwrite[row * PITCH + col] = (short)f2bf(hv);
            }
        }
        __syncthreads();   // h_t visible to all waves before t+1 reads
    }
}

// ---------------- host ----------------
extern "C" void kernel_launch(void* const* d_in, const int* in_sizes, int n_in,
                              void* d_out, int out_size, void* d_ws, size_t ws_size,
                              hipStream_t stream) {
    const float* x    = (const float*)d_in[0];
    const float* kern = (const float*)d_in[1];
    const float* A    = (const float*)d_in[2];
    const float* Bv   = (const float*)d_in[3];
    const float* Wh   = (const float*)d_in[4];
    const float* Uh   = (const float*)d_in[5];
    const float* bh   = (const float*)d_in[6];
    float* out = (float*)d_out;

    char* ws = (char*)d_ws;
    size_t off = 0;
    auto walloc = [&](size_t bytes) {
        void* p = ws + off;
        off += (bytes + 255) & ~(size_t)255;
        return p;
    };
    float* u             = (float*)walloc(sizeof(float) * NROWS * T_SEQ);        // 8 MB
    float* m_state       = (float*)walloc(sizeof(float) * NROWS * 64);           // 512 KB
    unsigned short* Wh2T = (unsigned short*)walloc(sizeof(short) * HID * KDIM);  // 4 MB
    unsigned short* UhbT = (unsigned short*)walloc(sizeof(short) * HID * HID);   // 512 KB
    unsigned short* m_ch = (unsigned short*)walloc(sizeof(short) * (size_t)TCH * 64 * KDIM); // 64 MB
    (void)ws_size; (void)in_sizes; (void)n_in; (void)out_size;

    k0_convert<<<2048, 256, 0, stream>>>(Wh, Uh, Wh2T, UhbT);
    k1_ugemm<<<1024, 256, 0, stream>>>(x, kern, u);
    for (int c = 0; c < NCHUNK; ++c) {
        k2_mscan<<<256, 256, 0, stream>>>(u, A, Bv, m_state, m_ch, c * TCH);
        dim3 g3(64, 4);
        k3_gemm<<<g3, 256, 0, stream>>>(m_ch, Wh2T, bh, out, c * TCH);
    }
    k4_hrec<<<4, 512, 0, stream>>>(UhbT, out);
}

// Round 6
// 4097.578 us; speedup vs baseline: 2.8427x; 1.8915x over previous
//
#include <hip/hip_runtime.h>
#include <hip/hip_bf16.h>

// LMU cell, MI355X. Phases:
//  K0: convert Wh -> Wh2T (bf16, [512 n][4096 k], Wh stacked twice for hi/lo m split),
//      Uh -> UhbT (bf16, transposed [col][k]).
//  K1: u[bm][t] = x@kernel  (f32)
//  K2: sequential m-scan over t (f32 state in LDS, A columns in VGPRs),
//      writes m as bf16 hi/lo into chunk buffer [128*64 rows][4096]
//  K3: pre = m@Wh + bh as bf16 MFMA GEMM (K=4096), writes pre INTO d_out[b][t][h]
//  K4: h_t = tanh(pre_t + h_{t-1}@Uh), batch-split 4 blocks x 16 batches,
//      self-contained per block (no inter-block sync). Uh FULLY RESIDENT:
//      196 VGPRs/lane pin 3.06 of 4 col-tiles, LDS holds the rest
//      (nt=3, kt=0..14). Zero per-step global Uh traffic. Fast tanh via
//      v_exp_f32 + v_rcp_f32. h double-buffered in LDS, 1 barrier/step.

#define T_SEQ 1024
#define BATCHN 64
#define MEMD 32
#define ORD 64
#define HID 512
#define DIN 128
#define NROWS 2048            // BATCHN*MEMD
#define KDIM 4096             // 2*MEMD*ORD (hi | lo)
#define TCH 128
#define NCHUNK 8
#define PITCH 520             // LDS row pitch (shorts) for [16][512] bf16 tile

typedef __attribute__((ext_vector_type(4))) float f32x4;
typedef __attribute__((ext_vector_type(8))) __bf16 bf16x8;

static __device__ __forceinline__ unsigned short f2bf(float f) {
    __hip_bfloat16 h = __float2bfloat16(f);
    return *reinterpret_cast<unsigned short*>(&h);
}
static __device__ __forceinline__ float bf2f(unsigned short s) {
    __hip_bfloat16 h = *reinterpret_cast<__hip_bfloat16*>(&s);
    return __bfloat162float(h);
}
// tanh(x) = 1 - 2/(exp(2x)+1); v_exp_f32 + v_rcp_f32, |err| ~1e-6 (<< bf16 h rounding)
static __device__ __forceinline__ float fast_tanh(float x) {
    float e = __expf(2.0f * x);
    return 1.0f - 2.0f * __builtin_amdgcn_rcpf(e + 1.0f);
}

// ---------------- K0: weight conversion ----------------
__global__ __launch_bounds__(256) void k0_convert(
        const float* __restrict__ Wh, const float* __restrict__ Uh,
        unsigned short* __restrict__ Wh2T, unsigned short* __restrict__ UhbT) {
    const int total = HID * KDIM + HID * HID;
    for (int idx = blockIdx.x * 256 + threadIdx.x; idx < total; idx += gridDim.x * 256) {
        if (idx < HID * KDIM) {
            int n = idx >> 12;          // /4096
            int k = idx & 4095;
            int ks = (k >= 2048) ? (k - 2048) : k;   // Wh stacked twice
            Wh2T[idx] = f2bf(Wh[(size_t)ks * HID + n]);
        } else {
            int j = idx - HID * KDIM;   // j = col*512 + k
            int col = j >> 9, k = j & 511;
            UhbT[j] = f2bf(Uh[(size_t)k * HID + col]);
        }
    }
}

// ---------------- K1: u = x @ kernel -> u[bm][t] ----------------
__global__ __launch_bounds__(256) void k1_ugemm(
        const float* __restrict__ x, const float* __restrict__ kern,
        float* __restrict__ u) {
    __shared__ float xs[64 * 128];
    __shared__ float kT[32 * 129];
    const int b = blockIdx.x >> 4;
    const int tt = blockIdx.x & 15;
    const int t0 = tt * 64;
    const int tid = threadIdx.x;

    const float4* xg = reinterpret_cast<const float4*>(x + ((size_t)b * T_SEQ + t0) * DIN);
    float4* xs4 = reinterpret_cast<float4*>(xs);
    #pragma unroll
    for (int r = 0; r < 8; ++r) xs4[r * 256 + tid] = xg[r * 256 + tid];
    #pragma unroll
    for (int r = 0; r < 16; ++r) {
        int idx = r * 256 + tid;        // 4096 = 128 d * 32 m
        int d = idx >> 5, m = idx & 31;
        kT[m * 129 + d] = kern[idx];
    }
    __syncthreads();

    const int m = tid & 31, tq = tid >> 5;
    float acc[8];
    #pragma unroll
    for (int i = 0; i < 8; ++i) acc[i] = 0.f;
    #pragma unroll
    for (int d4 = 0; d4 < 32; ++d4) {
        float k0 = kT[m * 129 + d4 * 4 + 0];
        float k1 = kT[m * 129 + d4 * 4 + 1];
        float k2 = kT[m * 129 + d4 * 4 + 2];
        float k3 = kT[m * 129 + d4 * 4 + 3];
        #pragma unroll
        for (int i = 0; i < 8; ++i) {
            float4 xv = xs4[(tq * 8 + i) * 32 + d4];
            acc[i] += xv.x * k0 + xv.y * k1 + xv.z * k2 + xv.w * k3;
        }
    }
    #pragma unroll
    for (int i = 0; i < 8; ++i)
        u[((size_t)(b * MEMD + m)) * T_SEQ + t0 + tq * 8 + i] = acc[i];
}

// ---------------- K2: m-scan (f32), writes bf16 hi/lo ----------------
__global__ __launch_bounds__(256, 1) void k2_mscan(
        const float* __restrict__ u, const float* __restrict__ A,
        const float* __restrict__ Bv, float* __restrict__ m_state,
        unsigned short* __restrict__ m_buf, int t0) {
    __shared__ float mbuf[2][8][64];
    __shared__ float ul[8][128];
    const int tid = threadIdx.x;
    const int wv = tid >> 6, half = (tid >> 5) & 1, pl = tid & 31;
    const int rl = wv * 2 + half;           // local row 0..7
    const int r = blockIdx.x * 8 + rl;      // global row (b*32+mem)
    const int p0 = pl * 2;

    float A0[64], A1[64];
    #pragma unroll
    for (int o = 0; o < 64; ++o) {
        A0[o] = A[o * 64 + p0];
        A1[o] = A[o * 64 + p0 + 1];
    }
    const float B0 = Bv[p0], B1 = Bv[p0 + 1];

    {   // stage u chunk: [8 rows][128 t]
        int row = tid >> 5, c4 = (tid & 31) * 4;
        *(float4*)&ul[row][c4] =
            *(const float4*)&u[(size_t)(blockIdx.x * 8 + row) * T_SEQ + t0 + c4];
    }
    float mc0, mc1;
    if (t0 == 0) { mc0 = 0.f; mc1 = 0.f; }
    else { mc0 = m_state[r * 64 + p0]; mc1 = m_state[r * 64 + p0 + 1]; }
    mbuf[0][rl][p0] = mc0;
    mbuf[0][rl][p0 + 1] = mc1;
    __syncthreads();

    const int b = r >> 5, mem = r & 31;
    int cur = 0;
    for (int tl = 0; tl < TCH; ++tl) {
        const float ut = ul[rl][tl];
        float a0 = ut * B0, a1 = ut * B1;
        const float4* mrow = (const float4*)&mbuf[cur][rl][0];
        #pragma unroll
        for (int o4 = 0; o4 < 16; ++o4) {
            float4 mv = mrow[o4];
            a0 += mv.x * A0[o4 * 4] + mv.y * A0[o4 * 4 + 1] + mv.z * A0[o4 * 4 + 2] + mv.w * A0[o4 * 4 + 3];
            a1 += mv.x * A1[o4 * 4] + mv.y * A1[o4 * 4 + 1] + mv.z * A1[o4 * 4 + 2] + mv.w * A1[o4 * 4 + 3];
        }
        size_t rowg = (size_t)(tl * 64 + b) * KDIM + mem * 64 + p0;
        unsigned short h0 = f2bf(a0), h1 = f2bf(a1);
        float f0 = a0 - bf2f(h0);
        float f1 = a1 - bf2f(h1);
        ushort2 hv; hv.x = h0; hv.y = h1;
        ushort2 lv; lv.x = f2bf(f0); lv.y = f2bf(f1);
        *(ushort2*)&m_buf[rowg] = hv;
        *(ushort2*)&m_buf[rowg + 2048] = lv;
        mbuf[cur ^ 1][rl][p0] = a0;
        mbuf[cur ^ 1][rl][p0 + 1] = a1;
        mc0 = a0; mc1 = a1;
        cur ^= 1;
        __syncthreads();
    }
    m_state[r * 64 + p0] = mc0;
    m_state[r * 64 + p0 + 1] = mc1;
}

// ---------------- K3: pre = m @ Wh + bh  (bf16 MFMA, K=4096) ----------------
__global__ __launch_bounds__(256, 1) void k3_gemm(
        const unsigned short* __restrict__ m_chunk,
        const unsigned short* __restrict__ Wh2T,
        const float* __restrict__ bh,
        float* __restrict__ out, int t0) {
    __shared__ short As[128 * 72];
    __shared__ short Bs[128 * 72];
    const int tid = threadIdx.x;
    const int l = tid & 63, wv = tid >> 6;
    const int wr = wv >> 1, wc = wv & 1;
    const int row0 = blockIdx.x * 128, n0 = blockIdx.y * 128;

    f32x4 acc[4][4];
    #pragma unroll
    for (int i = 0; i < 4; ++i)
        #pragma unroll
        for (int j = 0; j < 4; ++j)
            acc[i][j] = (f32x4){0.f, 0.f, 0.f, 0.f};

    for (int k0 = 0; k0 < KDIM; k0 += 64) {
        int4 av[4], bv[4];
        #pragma unroll
        for (int rI = 0; rI < 4; ++rI) {
            int idx = rI * 256 + tid;
            int rr = idx >> 3, l8 = idx & 7;
            av[rI] = *(const int4*)(m_chunk + (size_t)(row0 + rr) * KDIM + k0 + l8 * 8);
            bv[rI] = *(const int4*)(Wh2T + (size_t)(n0 + rr) * KDIM + k0 + l8 * 8);
        }
        __syncthreads();
        #pragma unroll
        for (int rI = 0; rI < 4; ++rI) {
            int idx = rI * 256 + tid;
            int rr = idx >> 3, l8 = idx & 7;
            *(int4*)(As + rr * 72 + l8 * 8) = av[rI];
            *(int4*)(Bs + rr * 72 + l8 * 8) = bv[rI];
        }
        __syncthreads();
        #pragma unroll
        for (int kk = 0; kk < 2; ++kk) {
            bf16x8 af[4], bf[4];
            #pragma unroll
            for (int mi = 0; mi < 4; ++mi)
                af[mi] = *(const bf16x8*)(As + (wr * 64 + mi * 16 + (l & 15)) * 72 + kk * 32 + (l >> 4) * 8);
            #pragma unroll
            for (int ni = 0; ni < 4; ++ni)
                bf[ni] = *(const bf16x8*)(Bs + (wc * 64 + ni * 16 + (l & 15)) * 72 + kk * 32 + (l >> 4) * 8);
            #pragma unroll
            for (int mi = 0; mi < 4; ++mi)
                #pragma unroll
                for (int ni = 0; ni < 4; ++ni)
                    acc[mi][ni] = __builtin_amdgcn_mfma_f32_16x16x32_bf16(af[mi], bf[ni], acc[mi][ni], 0, 0, 0);
        }
    }
    #pragma unroll
    for (int ni = 0; ni < 4; ++ni) {
        int col = n0 + wc * 64 + ni * 16 + (l & 15);
        float bhv = bh[col];
        #pragma unroll
        for (int mi = 0; mi < 4; ++mi) {
            #pragma unroll
            for (int e = 0; e < 4; ++e) {
                int gr = row0 + wr * 64 + mi * 16 + (l >> 4) * 4 + e; // chunk-local (t,b) row
                int t = t0 + (gr >> 6), b = gr & 63;
                out[((size_t)b * T_SEQ + t) * HID + col] = acc[mi][ni][e] + bhv;
            }
        }
    }
}

// ---------------- K4: h recurrence, batch-split, Uh fully resident --------
// 4 blocks x 512 thr (8 waves, 1 block/CU). Block bg owns batches bg*16..+15,
// computes full 512-wide h each step. Wave w owns cols [w*64, w*64+64).
// B-operand (Uh) residency: nt=0,1,2 + (nt=3,kt=15) pinned in VGPRs (196),
// (nt=3, kt=0..14) in LDS (122,880 B, wave-contiguous conflict-free).
// h double-buffered in LDS (PITCH=520), one __syncthreads per step.
__global__ __launch_bounds__(512, 2) void k4_hrec(
        const unsigned short* __restrict__ UhbT,
        float* __restrict__ out) {
    __shared__ short uh3[8 * 15 * 512];     // [w][kt][l*8] shorts = 122,880 B
    __shared__ short hlds[2][16 * PITCH];   // 33,280 B   (total 156,160 B)
    const int tid = threadIdx.x;
    const int l = tid & 63, w = tid >> 6;   // wave 0..7
    const int bg = blockIdx.x;              // 0..3
    const int b0 = bg * 16;
    const int lr = l & 15, lq = l >> 4;     // frag row / k-quad
    const int colBase = w * 64;

    // ---- init: pin B-frags in VGPRs (nt=0..2 all kt, + nt=3 kt=15) ----
    const unsigned short* u0 = UhbT + ((size_t)(colBase +  0 + lr) << 9) + lq * 8;
    const unsigned short* u1 = UhbT + ((size_t)(colBase + 16 + lr) << 9) + lq * 8;
    const unsigned short* u2 = UhbT + ((size_t)(colBase + 32 + lr) << 9) + lq * 8;
    const unsigned short* u3 = UhbT + ((size_t)(colBase + 48 + lr) << 9) + lq * 8;
    bf16x8 bp0[16], bp1[16], bp2[16], bp3_15;
    #pragma unroll
    for (int kt = 0; kt < 16; ++kt) {
        bp0[kt] = *(const bf16x8*)(u0 + kt * 32);
        bp1[kt] = *(const bf16x8*)(u1 + kt * 32);
        bp2[kt] = *(const bf16x8*)(u2 + kt * 32);
    }
    bp3_15 = *(const bf16x8*)(u3 + 15 * 32);
    // ---- stage (nt=3, kt=0..14) into LDS, wave-contiguous ----
    short* myuh3 = uh3 + w * 15 * 512;      // 512 shorts (1 KB) per kt
    #pragma unroll
    for (int kt = 0; kt < 15; ++kt)
        *(int4*)(myuh3 + kt * 512 + l * 8) = *(const int4*)(u3 + kt * 32);
    __syncthreads();

    // per-lane out row pointers (advance by HID each step); reused for store
    float* rp[4];
    #pragma unroll
    for (int e = 0; e < 4; ++e)
        rp[e] = out + (size_t)(b0 + lq * 4 + e) * T_SEQ * HID + colBase + lr;

    for (int t = 0; t < T_SEQ; ++t) {
        // prefetch pre_t for this lane's 16 output slots
        float pv[4][4];
        #pragma unroll
        for (int nt = 0; nt < 4; ++nt)
            #pragma unroll
            for (int e = 0; e < 4; ++e)
                pv[nt][e] = rp[e][nt * 16];

        f32x4 acc[4];
        #pragma unroll
        for (int nt = 0; nt < 4; ++nt) acc[nt] = (f32x4){0.f, 0.f, 0.f, 0.f};

        if (t > 0) {
            const short* hread = hlds[(t + 1) & 1];   // h_{t-1}
            #pragma unroll
            for (int kt = 0; kt < 16; ++kt) {
                bf16x8 a = *(const bf16x8*)(hread + lr * PITCH + kt * 32 + lq * 8);
                acc[0] = __builtin_amdgcn_mfma_f32_16x16x32_bf16(a, bp0[kt], acc[0], 0, 0, 0);
                acc[1] = __builtin_amdgcn_mfma_f32_16x16x32_bf16(a, bp1[kt], acc[1], 0, 0, 0);
                acc[2] = __builtin_amdgcn_mfma_f32_16x16x32_bf16(a, bp2[kt], acc[2], 0, 0, 0);
                bf16x8 b3;
                if (kt < 15) b3 = *(const bf16x8*)(myuh3 + kt * 512 + l * 8);
                else         b3 = bp3_15;
                acc[3] = __builtin_amdgcn_mfma_f32_16x16x32_bf16(a, b3, acc[3], 0, 0, 0);
            }
        }
        // h_t -> other LDS buffer + out (in place over pre)
        short* hw = &hlds[t & 1][lq * 4 * PITCH + colBase + lr];
        #pragma unroll
        for (int nt = 0; nt < 4; ++nt) {
            #pragma unroll
            for (int e = 0; e < 4; ++e) {
                float hv = fast_tanh(pv[nt][e] + acc[nt][e]);
                rp[e][nt * 16] = hv;
                hw[e * PITCH + nt * 16] = (short)f2bf(hv);
            }
        }
        #pragma unroll
        for (int e = 0; e < 4; ++e) rp[e] += HID;
        __syncthreads();   // h_t visible to all waves before t+1 reads
    }
}

// ---------------- host ----------------
extern "C" void kernel_launch(void* const* d_in, const int* in_sizes, int n_in,
                              void* d_out, int out_size, void* d_ws, size_t ws_size,
                              hipStream_t stream) {
    const float* x    = (const float*)d_in[0];
    const float* kern = (const float*)d_in[1];
    const float* A    = (const float*)d_in[2];
    const float* Bv   = (const float*)d_in[3];
    const float* Wh   = (const float*)d_in[4];
    const float* Uh   = (const float*)d_in[5];
    const float* bh   = (const float*)d_in[6];
    float* out = (float*)d_out;

    char* ws = (char*)d_ws;
    size_t off = 0;
    auto walloc = [&](size_t bytes) {
        void* p = ws + off;
        off += (bytes + 255) & ~(size_t)255;
        return p;
    };
    float* u             = (float*)walloc(sizeof(float) * NROWS * T_SEQ);        // 8 MB
    float* m_state       = (float*)walloc(sizeof(float) * NROWS * 64);           // 512 KB
    unsigned short* Wh2T = (unsigned short*)walloc(sizeof(short) * HID * KDIM);  // 4 MB
    unsigned short* UhbT = (unsigned short*)walloc(sizeof(short) * HID * HID);   // 512 KB
    unsigned short* m_ch = (unsigned short*)walloc(sizeof(short) * (size_t)TCH * 64 * KDIM); // 64 MB
    (void)ws_size; (void)in_sizes; (void)n_in; (void)out_size;

    k0_convert<<<2048, 256, 0, stream>>>(Wh, Uh, Wh2T, UhbT);
    k1_ugemm<<<1024, 256, 0, stream>>>(x, kern, u);
    for (int c = 0; c < NCHUNK; ++c) {
        k2_mscan<<<256, 256, 0, stream>>>(u, A, Bv, m_state, m_ch, c * TCH);
        dim3 g3(64, 4);
        k3_gemm<<<g3, 256, 0, stream>>>(m_ch, Wh2T, bh, out, c * TCH);
    }
    k4_hrec<<<4, 512, 0, stream>>>(UhbT, out);
}